// Round 8
// baseline (318.908 us; speedup 1.0000x reference)
//
#include <hip/hip_runtime.h>
#include <math.h>

#define Hh 24
#define Ww 24
#define Nn 576
#define Dd 1024
#define Bb 32
#define Kk 256
#define Mm 128
#define TOKSTRIDE (577 * 1024)

// Per-batch scratch lives INSIDE d_out: batch b owns out[b*Mm*Dd .. (b+1)*Mm*Dd).
// Scratch is consumed (via LDS/regs) before the plan/output phases overwrite
// the rows. d_ws is NOT used.
#define R0_OFF 0       // roots0           : 576 int
#define MEMB_OFF 1152  // members (sorted) : 576 int
#define OFFS_OFF 1728  // offsets per root : 576 int
#define ORD_OFF 2304   // ord_idx (top-256): 256 int
#define CNT_OFF 2560   // cnt_sel          : 256 int
#define P_OFF 2944     // p = patch.u      : 576 float
#define QC_OFF 3776    // qcls             : 1024 float
#define U_OFF 4800     // u = qcls.v_w     : 1024 float
#define T_OFF 5824     // t = qcls.v_b     : 1 float
#define UP_OFF 6144    // u partials       : 8*1024 float (ends 14336 < 131072)

__device__ __forceinline__ float* batch_base(float* out, int b) {
  return out + (size_t)b * Mm * Dd;
}

// ---------------------------------------------------------------------------
// K4 (runs FIRST): qcls[b,dp] = cls[b]·q_w[dp,:] + q_b[dp]. One block per dp;
//     4 waves, each handles 8 batches (q_w row reused in regs).
// ---------------------------------------------------------------------------
__global__ __launch_bounds__(256) void qcls_kernel(
    const float* __restrict__ tok2d, const float* __restrict__ q_w,
    const float* __restrict__ q_b, float* __restrict__ outb) {
  int dp = blockIdx.x;
  int wave = threadIdx.x >> 6;
  int lane = threadIdx.x & 63;
  float4 qv[4];
#pragma unroll
  for (int i = 0; i < 4; i++)
    qv[i] = *(const float4*)(q_w + (size_t)dp * Dd + lane * 4 + 256 * i);
  float qb = q_b[dp];
  for (int bb = 0; bb < 8; bb++) {
    int b = wave * 8 + bb;
    const float* cls = tok2d + (size_t)b * TOKSTRIDE;
    float a = 0.f;
#pragma unroll
    for (int i = 0; i < 4; i++) {
      float4 cv = *(const float4*)(cls + lane * 4 + 256 * i);
      a += qv[i].x * cv.x + qv[i].y * cv.y + qv[i].z * cv.z + qv[i].w * cv.w;
    }
#pragma unroll
    for (int s = 32; s > 0; s >>= 1) a += __shfl_down(a, s, 64);
    if (lane == 0) batch_base(outb, b)[QC_OFF + dp] = a + qb;
  }
}

// ---------------------------------------------------------------------------
// K5: u partials: up[chunk][d] = sum_{dp in chunk} qcls[dp] * v_w[dp,d].
// ---------------------------------------------------------------------------
__global__ __launch_bounds__(256) void u_part_kernel(const float* __restrict__ v_w,
                                                     float* __restrict__ outb) {
  int b = blockIdx.x >> 3;
  int chunk = blockIdx.x & 7;
  int tid = threadIdx.x;
  int d0 = tid * 4;
  float* basef = batch_base(outb, b);
  __shared__ float qs[128];
  if (tid < 128) qs[tid] = basef[QC_OFF + chunk * 128 + tid];
  __syncthreads();
  float4 a = make_float4(0.f, 0.f, 0.f, 0.f);
#pragma unroll 4
  for (int dpl = 0; dpl < 128; dpl++) {
    int dp = chunk * 128 + dpl;
    float4 vv = *(const float4*)(v_w + (size_t)dp * Dd + d0);
    float qq = qs[dpl];
    a.x += qq * vv.x; a.y += qq * vv.y; a.z += qq * vv.z; a.w += qq * vv.w;
  }
  *(float4*)(basef + UP_OFF + chunk * Dd + d0) = a;
}

// ---------------------------------------------------------------------------
// K6: combine u partials + t[b] = qcls[b]·v_b. One block per batch.
// ---------------------------------------------------------------------------
__global__ __launch_bounds__(256) void combine_ut_kernel(
    const float* __restrict__ v_b, float* __restrict__ outb) {
  int b = blockIdx.x;
  int tid = threadIdx.x;
  float* basef = batch_base(outb, b);
  int d0 = tid * 4;
  float4 s = make_float4(0.f, 0.f, 0.f, 0.f);
#pragma unroll
  for (int c = 0; c < 8; c++) {
    float4 v = *(const float4*)(basef + UP_OFF + c * Dd + d0);
    s.x += v.x; s.y += v.y; s.z += v.z; s.w += v.w;
  }
  *(float4*)(basef + U_OFF + d0) = s;

  float a = 0.f;
  for (int i = tid; i < Dd; i += 256) a += basef[QC_OFF + i] * v_b[i];
  __shared__ float sh[256];
  sh[tid] = a;
  __syncthreads();
  for (int st = 128; st > 0; st >>= 1) {
    if (tid < st) sh[tid] += sh[tid + st];
    __syncthreads();
  }
  if (tid == 0) basef[T_OFF] = sh[0];
}

// ---------------------------------------------------------------------------
// K1: fused affinity + p. Block = (b, y, octet of 8 x's); 4 waves = 4
//     d-chunks of 256. Register-resident set kept SMALL (~40 floats: dw 36 +
//     u 4) so the compiler actually keeps it live across the 8-token loop
//     (R7's 76-float set spilled to LDS). pw_w (36 KB) staged in LDS once per
//     block, read conflict-free as float4 per lane in the pointwise loop.
//     Per token: 9 patch float4 loads, conv, 9 pointwise logits + p partial
//     (center·u), 10-value shuffle reduce -> LDS. One final syncthreads;
//     threads 0..7 finalize (softmax + duplicate-accumulated clipped-neighbor
//     argmax, tie -> lowest col) -> roots0 + p.
// ---------------------------------------------------------------------------
__global__ __launch_bounds__(256, 3) void affinity_p_root_kernel(
    const float* __restrict__ tok2d, const float* __restrict__ dw_w,
    const float* __restrict__ pw_w, const float* __restrict__ pw_b,
    float* __restrict__ outb) {
  int wave = threadIdx.x >> 6;  // d-chunk
  int lane = threadIdx.x & 63;
  int blk = blockIdx.x;  // [0, Bb*Hh*3)
  int b = blk / (Hh * 3);
  int rem = blk % (Hh * 3);
  int y = rem / 3;
  int x0 = (rem % 3) * 8;
  int d0 = wave * 256 + lane * 4;
  const float* patch = tok2d + (size_t)b * TOKSTRIDE + Dd;  // skip cls token
  float* basef = batch_base(outb, b);

  // stage pw_w (9 x 1024 = 36 KB) into LDS once per block
  __shared__ float spw[9 * Dd];
  {
    const float4* src = (const float4*)pw_w;
    float4* dst = (float4*)spw;
    for (int i = threadIdx.x; i < 9 * Dd / 4; i += 256) dst[i] = src[i];
  }

  // register-resident: depthwise weights (36 floats) + u (4 floats)
  union { float4 v[9]; float f[36]; } w;
  const float4* dwp = (const float4*)(dw_w + (size_t)d0 * 9);
#pragma unroll
  for (int j = 0; j < 9; j++) w.v[j] = dwp[j];
  float4 u4 = *(const float4*)(basef + U_OFF + d0);

  __shared__ float red[8][4][10];
  __syncthreads();  // spw ready

  for (int t = 0; t < 8; t++) {
    int x = x0 + t;
    float4 cc = make_float4(0.f, 0.f, 0.f, 0.f);
    float4 center = make_float4(0.f, 0.f, 0.f, 0.f);
#pragma unroll
    for (int ky = 0; ky < 3; ky++) {
      int yy = y + ky - 1;
      if (yy < 0 || yy >= Hh) continue;  // wave-uniform
#pragma unroll
      for (int kx = 0; kx < 3; kx++) {
        int xx = x + kx - 1;
        if (xx < 0 || xx >= Ww) continue;  // wave-uniform
        float4 pv = *(const float4*)(patch + (size_t)(yy * Ww + xx) * Dd + d0);
        int k = ky * 3 + kx;
        cc.x += pv.x * w.f[k];
        cc.y += pv.y * w.f[9 + k];
        cc.z += pv.z * w.f[18 + k];
        cc.w += pv.w * w.f[27 + k];
        if (k == 4) center = pv;
      }
    }
    float acc[10];
#pragma unroll
    for (int o = 0; o < 9; o++) {
      float4 pwv = *(const float4*)&spw[o * Dd + d0];
      acc[o] = cc.x * pwv.x + cc.y * pwv.y + cc.z * pwv.z + cc.w * pwv.w;
    }
    acc[9] = center.x * u4.x + center.y * u4.y + center.z * u4.z + center.w * u4.w;
#pragma unroll
    for (int s = 32; s > 0; s >>= 1) {
#pragma unroll
      for (int o = 0; o < 10; o++) acc[o] += __shfl_down(acc[o], s, 64);
    }
    if (lane == 0) {
#pragma unroll
      for (int o = 0; o < 10; o++) red[t][wave][o] = acc[o];
    }
  }
  __syncthreads();

  if (threadIdx.x < 8) {
    int t = threadIdx.x;
    int x = x0 + t;
    int n = y * Ww + x;
    float l[9], q[9];
    float mx = -INFINITY;
#pragma unroll
    for (int o = 0; o < 9; o++) {
      l[o] = red[t][0][o] + red[t][1][o] + red[t][2][o] + red[t][3][o] + pw_b[o];
      mx = fmaxf(mx, l[o]);
    }
    float ssum = 0.f;
#pragma unroll
    for (int o = 0; o < 9; o++) {
      q[o] = expf(l[o] - mx);
      ssum += q[o];
    }
#pragma unroll
    for (int o = 0; o < 9; o++) q[o] = q[o] / ssum;

    // accumulate into distinct clipped columns, ascending-o order
    int cols[9];
    float vals[9];
    int ncol = 0;
    for (int o = 0; o < 9; o++) {
      int dy = o / 3 - 1, dx = o % 3 - 1;
      int ny = min(max(y + dy, 0), Hh - 1);
      int nx = min(max(x + dx, 0), Ww - 1);
      int col = ny * Ww + nx;
      int f = -1;
      for (int j = 0; j < ncol; j++)
        if (cols[j] == col) { f = j; break; }
      if (f >= 0) vals[f] += q[o];
      else { cols[ncol] = col; vals[ncol] = q[o]; ncol++; }
    }
    // argmax, tie -> lowest column (all vals > 0, rest of row is 0)
    float best = -1.f;
    int bcol = 1 << 30;
    for (int j = 0; j < ncol; j++) {
      if (vals[j] > best || (vals[j] == best && cols[j] < bcol)) {
        best = vals[j];
        bcol = cols[j];
      }
    }
    ((int*)basef)[R0_OFF + n] = bcol;
    basef[P_OFF + n] = red[t][0][9] + red[t][1][9] + red[t][2][9] + red[t][3][9];
  }
}

// ---------------------------------------------------------------------------
// K2: 6x pointer jumping + counts + stable counting sort + top-256 of counts
//     (exact jax.lax.top_k tie semantics), fused. One block/batch, 576 thr.
// ---------------------------------------------------------------------------
__global__ __launch_bounds__(576) void cluster_topk_kernel(float* __restrict__ outb) {
  int b = blockIdx.x;
  int n = threadIdx.x;
  int* base = (int*)batch_base(outb, b);
  __shared__ int ra[Nn], rb[Nn], scnt[Nn], soff[Nn];
  ra[n] = base[R0_OFF + n];
  scnt[n] = 0;
  __syncthreads();
  for (int it = 0; it < 6; it++) {
    rb[n] = ra[ra[n]];
    __syncthreads();
    ra[n] = rb[n];
    __syncthreads();
  }
  int r = ra[n];
  atomicAdd(&scnt[r], 1);
  __syncthreads();

  // inclusive scan of scnt -> soff
  soff[n] = scnt[n];
  __syncthreads();
  for (int s = 1; s < Nn; s <<= 1) {
    int v = (n >= s) ? soff[n - s] : 0;
    __syncthreads();
    soff[n] += v;
    __syncthreads();
  }
  int excl = soff[n] - scnt[n];
  base[OFFS_OFF + n] = excl;
  int offr = soff[r] - scnt[r];
  int rk = 0;
  for (int m = 0; m < n; m++) rk += (ra[m] == r);
  base[MEMB_OFF + offr + rk] = n;

  // --- top-256 of counts (value desc, index asc), ascending-index output ---
  int cn = scnt[n];
  int rank = 0;
  for (int m = 0; m < Nn; m++) {
    int cm = scnt[m];
    rank += (cm > cn) || (cm == cn && m < n);
  }
  int sl = (rank < Kk) ? 1 : 0;
  rb[n] = sl;
  __syncthreads();
  // inclusive scan of sel
  for (int s = 1; s < Nn; s <<= 1) {
    int v = (n >= s) ? rb[n - s] : 0;
    __syncthreads();
    rb[n] += v;
    __syncthreads();
  }
  if (sl) {
    int pos = rb[n] - 1;
    base[ORD_OFF + pos] = n;
    base[CNT_OFF + pos] = cn;
  }
}

// ---------------------------------------------------------------------------
// K7: scores + top-128 (exact top_k ties) + per-row plan write, fused.
//     Plan phase striped over 4 waves.
// ---------------------------------------------------------------------------
__global__ __launch_bounds__(256) void scores_plan_kernel(float* __restrict__ outb) {
  int b = blockIdx.x;
  int tid = threadIdx.x;
  int wave = tid >> 6, lane = tid & 63;
  float* basef = batch_base(outb, b);
  int* base = (int*)basef;
  __shared__ int s_mem[Nn], s_off[Nn], s_ord[Kk], s_cnt[Kk], s_out[Mm];
  __shared__ float ss[Kk];
  __shared__ int sel[Kk];
  for (int i = tid; i < Nn; i += 256) {
    s_mem[i] = base[MEMB_OFF + i];
    s_off[i] = base[OFFS_OFF + i];
  }
  s_ord[tid] = base[ORD_OFF + tid];
  s_cnt[tid] = base[CNT_OFF + tid];
  float tt = basef[T_OFF];
  __syncthreads();

  // scores
  int idx = s_ord[tid];
  int c = s_cnt[tid];
  float s;
  if (c > 0) {
    int off = s_off[idx];
    float sum = 0.f;
    for (int j = 0; j < c; j++) sum += basef[P_OFF + s_mem[off + j]];
    s = (sum / (float)c + tt) * (1.0f / 32.0f);
  } else {
    s = -INFINITY;
  }
  ss[tid] = s;
  __syncthreads();

  // top-128 (value desc, index asc), ascending-index output
  float vk = ss[tid];
  int rank = 0;
  for (int m = 0; m < Kk; m++) {
    float vm = ss[m];
    rank += (vm > vk) || (vm == vk && m < tid);
  }
  sel[tid] = (rank < Mm) ? 1 : 0;
  __syncthreads();
  if (sel[tid]) {
    int pos = 0;
    for (int m = 0; m < tid; m++) pos += sel[m];
    s_out[pos] = tid;
  }
  __syncthreads();

  // plan: write [count, member ids...] into each of this batch's 128 rows
  for (int kp = wave; kp < Mm; kp += 4) {
    int k = s_out[kp];
    int kidx = s_ord[k];
    int kc = s_cnt[k];
    int koff = s_off[kidx];
    int* row = base + kp * Dd;
    if (lane == 0) row[0] = kc;
    for (int j = lane; j < kc; j += 64) row[1 + j] = s_mem[koff + j];
  }
}

// ---------------------------------------------------------------------------
// K8: output. One block per output row; reads its OWN row's plan into LDS,
//     then overwrites the row with the cluster mean. float4 over d.
// ---------------------------------------------------------------------------
__global__ __launch_bounds__(256) void output_kernel(
    const float* __restrict__ tok2d, float* __restrict__ outb) {
  int blk = blockIdx.x;  // b*Mm + kp
  int b = blk / Mm;
  int tid = threadIdx.x;
  float* rowf = outb + (size_t)blk * Dd;
  int* rowi = (int*)rowf;
  __shared__ int s_c;
  __shared__ int s_m[Nn];
  if (tid == 0) s_c = rowi[0];
  __syncthreads();
  int c = s_c;
  for (int j = tid; j < c; j += 256) s_m[j] = rowi[1 + j];
  __syncthreads();
  const float* patch = tok2d + (size_t)b * TOKSTRIDE + Dd;
  int d0 = tid * 4;
  float4 acc = make_float4(0.f, 0.f, 0.f, 0.f);
  for (int j = 0; j < c; j++) {
    float4 rv = *(const float4*)(patch + (size_t)s_m[j] * Dd + d0);
    acc.x += rv.x; acc.y += rv.y; acc.z += rv.z; acc.w += rv.w;
  }
  float inv = 1.0f / (float)max(c, 1);
  *(float4*)(rowf + d0) =
      make_float4(acc.x * inv, acc.y * inv, acc.z * inv, acc.w * inv);
}

// ---------------------------------------------------------------------------
extern "C" void kernel_launch(void* const* d_in, const int* in_sizes, int n_in,
                              void* d_out, int out_size, void* d_ws,
                              size_t ws_size, hipStream_t stream) {
  const float* tok2d = (const float*)d_in[0];
  const float* dw_w = (const float*)d_in[1];
  const float* pw_w = (const float*)d_in[2];
  const float* pw_b = (const float*)d_in[3];
  const float* q_w = (const float*)d_in[4];
  const float* q_b = (const float*)d_in[5];
  const float* v_w = (const float*)d_in[6];
  const float* v_b = (const float*)d_in[7];
  float* out = (float*)d_out;
  (void)d_ws; (void)ws_size;  // d_ws intentionally unused

  // u/t first (affinity's fused p-dot needs u)
  qcls_kernel<<<dim3(Dd), dim3(256), 0, stream>>>(tok2d, q_w, q_b, out);
  u_part_kernel<<<dim3(Bb * 8), dim3(256), 0, stream>>>(v_w, out);
  combine_ut_kernel<<<dim3(Bb), dim3(256), 0, stream>>>(v_b, out);
  affinity_p_root_kernel<<<dim3(Bb * Hh * 3), dim3(256), 0, stream>>>(
      tok2d, dw_w, pw_w, pw_b, out);
  cluster_topk_kernel<<<dim3(Bb), dim3(Nn), 0, stream>>>(out);
  scores_plan_kernel<<<dim3(Bb), dim3(256), 0, stream>>>(out);
  output_kernel<<<dim3(Bb * Mm), dim3(256), 0, stream>>>(tok2d, out);
}

// Round 9
// 307.463 us; speedup vs baseline: 1.0372x; 1.0372x over previous
//
#include <hip/hip_runtime.h>
#include <math.h>

#define Hh 24
#define Ww 24
#define Nn 576
#define Dd 1024
#define Bb 32
#define Kk 256
#define Mm 128
#define TOKSTRIDE (577 * 1024)

// Per-batch scratch lives INSIDE d_out: batch b owns out[b*Mm*Dd .. (b+1)*Mm*Dd).
// Scratch is consumed (via LDS/regs) before the plan/output phases overwrite
// the rows. d_ws is NOT used.
#define R0_OFF 0       // roots0           : 576 int
#define MEMB_OFF 1152  // members (sorted) : 576 int
#define OFFS_OFF 1728  // offsets per root : 576 int
#define ORD_OFF 2304   // ord_idx (top-256): 256 int
#define CNT_OFF 2560   // cnt_sel          : 256 int
#define P_OFF 2944     // p = patch.u      : 576 float
#define QC_OFF 3776    // qcls             : 1024 float
#define U_OFF 4800     // u = qcls.v_w     : 1024 float
#define T_OFF 5824     // t = qcls.v_b     : 1 float
#define UP_OFF 6144    // u partials       : 8*1024 float (ends 14336 < 131072)

__device__ __forceinline__ float* batch_base(float* out, int b) {
  return out + (size_t)b * Mm * Dd;
}

// Full-wave (64-lane) float sum via DPP — VALU pipe only, no LDS traffic.
// Canonical gfx9/CDNA sequence; result valid in lane 63.
__device__ __forceinline__ float wave_sum_dpp(float x) {
  int y;
  y = __builtin_amdgcn_update_dpp(0, __float_as_int(x), 0x111, 0xf, 0xf, true);
  x += __int_as_float(y);  // row_shr:1
  y = __builtin_amdgcn_update_dpp(0, __float_as_int(x), 0x112, 0xf, 0xf, true);
  x += __int_as_float(y);  // row_shr:2
  y = __builtin_amdgcn_update_dpp(0, __float_as_int(x), 0x114, 0xf, 0xf, true);
  x += __int_as_float(y);  // row_shr:4
  y = __builtin_amdgcn_update_dpp(0, __float_as_int(x), 0x118, 0xf, 0xf, true);
  x += __int_as_float(y);  // row_shr:8  -> lanes 15/31/47/63 hold row sums
  y = __builtin_amdgcn_update_dpp(0, __float_as_int(x), 0x142, 0xa, 0xf, true);
  x += __int_as_float(y);  // row_bcast:15 into rows 1,3
  y = __builtin_amdgcn_update_dpp(0, __float_as_int(x), 0x143, 0xc, 0xf, true);
  x += __int_as_float(y);  // row_bcast:31 into rows 2,3 -> lane 63 = total
  return x;
}

// ---------------------------------------------------------------------------
// K4 (runs FIRST): qcls[b,dp] = cls[b]·q_w[dp,:] + q_b[dp]. One block per dp;
//     4 waves, each handles 8 batches (q_w row reused in regs).
// ---------------------------------------------------------------------------
__global__ __launch_bounds__(256) void qcls_kernel(
    const float* __restrict__ tok2d, const float* __restrict__ q_w,
    const float* __restrict__ q_b, float* __restrict__ outb) {
  int dp = blockIdx.x;
  int wave = threadIdx.x >> 6;
  int lane = threadIdx.x & 63;
  float4 qv[4];
#pragma unroll
  for (int i = 0; i < 4; i++)
    qv[i] = *(const float4*)(q_w + (size_t)dp * Dd + lane * 4 + 256 * i);
  float qb = q_b[dp];
  for (int bb = 0; bb < 8; bb++) {
    int b = wave * 8 + bb;
    const float* cls = tok2d + (size_t)b * TOKSTRIDE;
    float a = 0.f;
#pragma unroll
    for (int i = 0; i < 4; i++) {
      float4 cv = *(const float4*)(cls + lane * 4 + 256 * i);
      a += qv[i].x * cv.x + qv[i].y * cv.y + qv[i].z * cv.z + qv[i].w * cv.w;
    }
    a = wave_sum_dpp(a);
    if (lane == 63) batch_base(outb, b)[QC_OFF + dp] = a + qb;
  }
}

// ---------------------------------------------------------------------------
// K5: u partials: up[chunk][d] = sum_{dp in chunk} qcls[dp] * v_w[dp,d].
// ---------------------------------------------------------------------------
__global__ __launch_bounds__(256) void u_part_kernel(const float* __restrict__ v_w,
                                                     float* __restrict__ outb) {
  int b = blockIdx.x >> 3;
  int chunk = blockIdx.x & 7;
  int tid = threadIdx.x;
  int d0 = tid * 4;
  float* basef = batch_base(outb, b);
  __shared__ float qs[128];
  if (tid < 128) qs[tid] = basef[QC_OFF + chunk * 128 + tid];
  __syncthreads();
  float4 a = make_float4(0.f, 0.f, 0.f, 0.f);
#pragma unroll 4
  for (int dpl = 0; dpl < 128; dpl++) {
    int dp = chunk * 128 + dpl;
    float4 vv = *(const float4*)(v_w + (size_t)dp * Dd + d0);
    float qq = qs[dpl];
    a.x += qq * vv.x; a.y += qq * vv.y; a.z += qq * vv.z; a.w += qq * vv.w;
  }
  *(float4*)(basef + UP_OFF + chunk * Dd + d0) = a;
}

// ---------------------------------------------------------------------------
// K6: combine u partials + t[b] = qcls[b]·v_b. One block per batch.
// ---------------------------------------------------------------------------
__global__ __launch_bounds__(256) void combine_ut_kernel(
    const float* __restrict__ v_b, float* __restrict__ outb) {
  int b = blockIdx.x;
  int tid = threadIdx.x;
  float* basef = batch_base(outb, b);
  int d0 = tid * 4;
  float4 s = make_float4(0.f, 0.f, 0.f, 0.f);
#pragma unroll
  for (int c = 0; c < 8; c++) {
    float4 v = *(const float4*)(basef + UP_OFF + c * Dd + d0);
    s.x += v.x; s.y += v.y; s.z += v.z; s.w += v.w;
  }
  *(float4*)(basef + U_OFF + d0) = s;

  float a = 0.f;
  for (int i = tid; i < Dd; i += 256) a += basef[QC_OFF + i] * v_b[i];
  __shared__ float sh[256];
  sh[tid] = a;
  __syncthreads();
  for (int st = 128; st > 0; st >>= 1) {
    if (tid < st) sh[tid] += sh[tid + st];
    __syncthreads();
  }
  if (tid == 0) basef[T_OFF] = sh[0];
}

// ---------------------------------------------------------------------------
// K1: fused affinity + p. Block = (b, y, octet of 8 x's); 4 waves = 4
//     d-chunks of 256. dw (36f) + u (4f) register-resident; pw_w (36 KB) in
//     LDS. Per token: 9 patch float4 loads, conv, 9 pointwise logits + p
//     partial (center·u), then a 10-value DPP wave reduction (VALU pipe, no
//     LDS shuffles) -> red[]. One final syncthreads; threads 0..7 finalize
//     (softmax + duplicate-accumulated clipped-neighbor argmax, tie -> lowest
//     col) -> roots0 + p.
// ---------------------------------------------------------------------------
__global__ __launch_bounds__(256, 3) void affinity_p_root_kernel(
    const float* __restrict__ tok2d, const float* __restrict__ dw_w,
    const float* __restrict__ pw_w, const float* __restrict__ pw_b,
    float* __restrict__ outb) {
  int wave = threadIdx.x >> 6;  // d-chunk
  int lane = threadIdx.x & 63;
  int blk = blockIdx.x;  // [0, Bb*Hh*3)
  int b = blk / (Hh * 3);
  int rem = blk % (Hh * 3);
  int y = rem / 3;
  int x0 = (rem % 3) * 8;
  int d0 = wave * 256 + lane * 4;
  const float* patch = tok2d + (size_t)b * TOKSTRIDE + Dd;  // skip cls token
  float* basef = batch_base(outb, b);

  // stage pw_w (9 x 1024 = 36 KB) into LDS once per block
  __shared__ float spw[9 * Dd];
  {
    const float4* src = (const float4*)pw_w;
    float4* dst = (float4*)spw;
    for (int i = threadIdx.x; i < 9 * Dd / 4; i += 256) dst[i] = src[i];
  }

  // register-resident: depthwise weights (36 floats) + u (4 floats)
  union { float4 v[9]; float f[36]; } w;
  const float4* dwp = (const float4*)(dw_w + (size_t)d0 * 9);
#pragma unroll
  for (int j = 0; j < 9; j++) w.v[j] = dwp[j];
  float4 u4 = *(const float4*)(basef + U_OFF + d0);

  __shared__ float red[8][4][10];
  __syncthreads();  // spw ready

  for (int t = 0; t < 8; t++) {
    int x = x0 + t;
    float4 cc = make_float4(0.f, 0.f, 0.f, 0.f);
    float4 center = make_float4(0.f, 0.f, 0.f, 0.f);
#pragma unroll
    for (int ky = 0; ky < 3; ky++) {
      int yy = y + ky - 1;
      if (yy < 0 || yy >= Hh) continue;  // wave-uniform
#pragma unroll
      for (int kx = 0; kx < 3; kx++) {
        int xx = x + kx - 1;
        if (xx < 0 || xx >= Ww) continue;  // wave-uniform
        float4 pv = *(const float4*)(patch + (size_t)(yy * Ww + xx) * Dd + d0);
        int k = ky * 3 + kx;
        cc.x += pv.x * w.f[k];
        cc.y += pv.y * w.f[9 + k];
        cc.z += pv.z * w.f[18 + k];
        cc.w += pv.w * w.f[27 + k];
        if (k == 4) center = pv;
      }
    }
    float acc[10];
#pragma unroll
    for (int o = 0; o < 9; o++) {
      float4 pwv = *(const float4*)&spw[o * Dd + d0];
      acc[o] = cc.x * pwv.x + cc.y * pwv.y + cc.z * pwv.z + cc.w * pwv.w;
    }
    acc[9] = center.x * u4.x + center.y * u4.y + center.z * u4.z + center.w * u4.w;
#pragma unroll
    for (int o = 0; o < 10; o++) acc[o] = wave_sum_dpp(acc[o]);
    if (lane == 63) {
#pragma unroll
      for (int o = 0; o < 10; o++) red[t][wave][o] = acc[o];
    }
  }
  __syncthreads();

  if (threadIdx.x < 8) {
    int t = threadIdx.x;
    int x = x0 + t;
    int n = y * Ww + x;
    float l[9], q[9];
    float mx = -INFINITY;
#pragma unroll
    for (int o = 0; o < 9; o++) {
      l[o] = red[t][0][o] + red[t][1][o] + red[t][2][o] + red[t][3][o] + pw_b[o];
      mx = fmaxf(mx, l[o]);
    }
    float ssum = 0.f;
#pragma unroll
    for (int o = 0; o < 9; o++) {
      q[o] = expf(l[o] - mx);
      ssum += q[o];
    }
#pragma unroll
    for (int o = 0; o < 9; o++) q[o] = q[o] / ssum;

    // accumulate into distinct clipped columns, ascending-o order
    int cols[9];
    float vals[9];
    int ncol = 0;
    for (int o = 0; o < 9; o++) {
      int dy = o / 3 - 1, dx = o % 3 - 1;
      int ny = min(max(y + dy, 0), Hh - 1);
      int nx = min(max(x + dx, 0), Ww - 1);
      int col = ny * Ww + nx;
      int f = -1;
      for (int j = 0; j < ncol; j++)
        if (cols[j] == col) { f = j; break; }
      if (f >= 0) vals[f] += q[o];
      else { cols[ncol] = col; vals[ncol] = q[o]; ncol++; }
    }
    // argmax, tie -> lowest column (all vals > 0, rest of row is 0)
    float best = -1.f;
    int bcol = 1 << 30;
    for (int j = 0; j < ncol; j++) {
      if (vals[j] > best || (vals[j] == best && cols[j] < bcol)) {
        best = vals[j];
        bcol = cols[j];
      }
    }
    ((int*)basef)[R0_OFF + n] = bcol;
    basef[P_OFF + n] = red[t][0][9] + red[t][1][9] + red[t][2][9] + red[t][3][9];
  }
}

// ---------------------------------------------------------------------------
// K2: 6x pointer jumping + counts + stable counting sort + top-256 of counts
//     (exact jax.lax.top_k tie semantics), fused. One block/batch, 576 thr.
// ---------------------------------------------------------------------------
__global__ __launch_bounds__(576) void cluster_topk_kernel(float* __restrict__ outb) {
  int b = blockIdx.x;
  int n = threadIdx.x;
  int* base = (int*)batch_base(outb, b);
  __shared__ int ra[Nn], rb[Nn], scnt[Nn], soff[Nn];
  ra[n] = base[R0_OFF + n];
  scnt[n] = 0;
  __syncthreads();
  for (int it = 0; it < 6; it++) {
    rb[n] = ra[ra[n]];
    __syncthreads();
    ra[n] = rb[n];
    __syncthreads();
  }
  int r = ra[n];
  atomicAdd(&scnt[r], 1);
  __syncthreads();

  // inclusive scan of scnt -> soff
  soff[n] = scnt[n];
  __syncthreads();
  for (int s = 1; s < Nn; s <<= 1) {
    int v = (n >= s) ? soff[n - s] : 0;
    __syncthreads();
    soff[n] += v;
    __syncthreads();
  }
  int excl = soff[n] - scnt[n];
  base[OFFS_OFF + n] = excl;
  int offr = soff[r] - scnt[r];
  int rk = 0;
  for (int m = 0; m < n; m++) rk += (ra[m] == r);
  base[MEMB_OFF + offr + rk] = n;

  // --- top-256 of counts (value desc, index asc), ascending-index output ---
  int cn = scnt[n];
  int rank = 0;
  for (int m = 0; m < Nn; m++) {
    int cm = scnt[m];
    rank += (cm > cn) || (cm == cn && m < n);
  }
  int sl = (rank < Kk) ? 1 : 0;
  rb[n] = sl;
  __syncthreads();
  // inclusive scan of sel
  for (int s = 1; s < Nn; s <<= 1) {
    int v = (n >= s) ? rb[n - s] : 0;
    __syncthreads();
    rb[n] += v;
    __syncthreads();
  }
  if (sl) {
    int pos = rb[n] - 1;
    base[ORD_OFF + pos] = n;
    base[CNT_OFF + pos] = cn;
  }
}

// ---------------------------------------------------------------------------
// K7: scores + top-128 (exact top_k ties) + per-row plan write, fused.
//     Plan phase striped over 4 waves.
// ---------------------------------------------------------------------------
__global__ __launch_bounds__(256) void scores_plan_kernel(float* __restrict__ outb) {
  int b = blockIdx.x;
  int tid = threadIdx.x;
  int wave = tid >> 6, lane = tid & 63;
  float* basef = batch_base(outb, b);
  int* base = (int*)basef;
  __shared__ int s_mem[Nn], s_off[Nn], s_ord[Kk], s_cnt[Kk], s_out[Mm];
  __shared__ float ss[Kk];
  __shared__ int sel[Kk];
  for (int i = tid; i < Nn; i += 256) {
    s_mem[i] = base[MEMB_OFF + i];
    s_off[i] = base[OFFS_OFF + i];
  }
  s_ord[tid] = base[ORD_OFF + tid];
  s_cnt[tid] = base[CNT_OFF + tid];
  float tt = basef[T_OFF];
  __syncthreads();

  // scores
  int idx = s_ord[tid];
  int c = s_cnt[tid];
  float s;
  if (c > 0) {
    int off = s_off[idx];
    float sum = 0.f;
    for (int j = 0; j < c; j++) sum += basef[P_OFF + s_mem[off + j]];
    s = (sum / (float)c + tt) * (1.0f / 32.0f);
  } else {
    s = -INFINITY;
  }
  ss[tid] = s;
  __syncthreads();

  // top-128 (value desc, index asc), ascending-index output
  float vk = ss[tid];
  int rank = 0;
  for (int m = 0; m < Kk; m++) {
    float vm = ss[m];
    rank += (vm > vk) || (vm == vk && m < tid);
  }
  sel[tid] = (rank < Mm) ? 1 : 0;
  __syncthreads();
  if (sel[tid]) {
    int pos = 0;
    for (int m = 0; m < tid; m++) pos += sel[m];
    s_out[pos] = tid;
  }
  __syncthreads();

  // plan: write [count, member ids...] into each of this batch's 128 rows
  for (int kp = wave; kp < Mm; kp += 4) {
    int k = s_out[kp];
    int kidx = s_ord[k];
    int kc = s_cnt[k];
    int koff = s_off[kidx];
    int* row = base + kp * Dd;
    if (lane == 0) row[0] = kc;
    for (int j = lane; j < kc; j += 64) row[1 + j] = s_mem[koff + j];
  }
}

// ---------------------------------------------------------------------------
// K8: output. One block per output row; reads its OWN row's plan into LDS,
//     then overwrites the row with the cluster mean. float4 over d.
// ---------------------------------------------------------------------------
__global__ __launch_bounds__(256) void output_kernel(
    const float* __restrict__ tok2d, float* __restrict__ outb) {
  int blk = blockIdx.x;  // b*Mm + kp
  int b = blk / Mm;
  int tid = threadIdx.x;
  float* rowf = outb + (size_t)blk * Dd;
  int* rowi = (int*)rowf;
  __shared__ int s_c;
  __shared__ int s_m[Nn];
  if (tid == 0) s_c = rowi[0];
  __syncthreads();
  int c = s_c;
  for (int j = tid; j < c; j += 256) s_m[j] = rowi[1 + j];
  __syncthreads();
  const float* patch = tok2d + (size_t)b * TOKSTRIDE + Dd;
  int d0 = tid * 4;
  float4 acc = make_float4(0.f, 0.f, 0.f, 0.f);
  for (int j = 0; j < c; j++) {
    float4 rv = *(const float4*)(patch + (size_t)s_m[j] * Dd + d0);
    acc.x += rv.x; acc.y += rv.y; acc.z += rv.z; acc.w += rv.w;
  }
  float inv = 1.0f / (float)max(c, 1);
  *(float4*)(rowf + d0) =
      make_float4(acc.x * inv, acc.y * inv, acc.z * inv, acc.w * inv);
}

// ---------------------------------------------------------------------------
extern "C" void kernel_launch(void* const* d_in, const int* in_sizes, int n_in,
                              void* d_out, int out_size, void* d_ws,
                              size_t ws_size, hipStream_t stream) {
  const float* tok2d = (const float*)d_in[0];
  const float* dw_w = (const float*)d_in[1];
  const float* pw_w = (const float*)d_in[2];
  const float* pw_b = (const float*)d_in[3];
  const float* q_w = (const float*)d_in[4];
  const float* q_b = (const float*)d_in[5];
  const float* v_w = (const float*)d_in[6];
  const float* v_b = (const float*)d_in[7];
  float* out = (float*)d_out;
  (void)d_ws; (void)ws_size;  // d_ws intentionally unused

  // u/t first (affinity's fused p-dot needs u)
  qcls_kernel<<<dim3(Dd), dim3(256), 0, stream>>>(tok2d, q_w, q_b, out);
  u_part_kernel<<<dim3(Bb * 8), dim3(256), 0, stream>>>(v_w, out);
  combine_ut_kernel<<<dim3(Bb), dim3(256), 0, stream>>>(v_b, out);
  affinity_p_root_kernel<<<dim3(Bb * Hh * 3), dim3(256), 0, stream>>>(
      tok2d, dw_w, pw_w, pw_b, out);
  cluster_topk_kernel<<<dim3(Bb), dim3(Nn), 0, stream>>>(out);
  scores_plan_kernel<<<dim3(Bb), dim3(256), 0, stream>>>(out);
  output_kernel<<<dim3(Bb * Mm), dim3(256), 0, stream>>>(tok2d, out);
}